// Round 1
// baseline (1678.289 us; speedup 1.0000x reference)
//
#include <hip/hip_runtime.h>
#include <hip/hip_fp16.h>

#define EDIM 256
#define HDIM 512
#define CDIM 50257

using half2_t = __attribute__((ext_vector_type(2))) _Float16;
using half8_t = __attribute__((ext_vector_type(8))) _Float16;
using float4_t = __attribute__((ext_vector_type(4))) float;

__device__ __forceinline__ float dot2(uint32_t w, uint32_t h, float acc) {
    return __builtin_amdgcn_fdot2(__builtin_bit_cast(half2_t, w),
                                  __builtin_bit_cast(half2_t, h), acc, false);
}

// ---------------------------------------------------------------------------
// Pack whh (f32 [512][512]) into f16 granules [g=0..63][tid=0..511][8 halves]
// scan thread `tid` (rg = tid>>3, c = tid&7) owns rows rg*8+jr, k in [c*64, c*64+64)
// granule g = jr*8 + i  holds  whh[rg*8 + (g>>3)][c*64 + (g&7)*8 + e]
// ---------------------------------------------------------------------------
__global__ void __launch_bounds__(256) pack_whh(const float* __restrict__ whh,
                                                _Float16* __restrict__ wpack) {
    int idx = blockIdx.x * blockDim.x + threadIdx.x;   // 0..32767
    int g = idx >> 9, t = idx & 511;
    int row = ((t >> 3) << 3) + (g >> 3);
    int k0 = ((t & 7) << 6) + ((g & 7) << 3);
    const float* src = whh + row * HDIM + k0;
    uint32_t d[4];
#pragma unroll
    for (int q = 0; q < 4; ++q) {
        half2_t p;
        p[0] = (_Float16)src[2 * q];
        p[1] = (_Float16)src[2 * q + 1];
        d[q] = __builtin_bit_cast(uint32_t, p);
    }
    uint4 v = make_uint4(d[0], d[1], d[2], d[3]);
    ((uint4*)wpack)[g * 512 + t] = v;
}

// ---------------------------------------------------------------------------
// z[t][r] = dot(wih[r,:], emb[id_t]) + bih[r] + bhh[r]   (fp32, parallel)
// t in [0,512): encoder, id=input_ids[t]; t==512: START=1; t>512: output_ids[t-513]
// ---------------------------------------------------------------------------
__global__ void __launch_bounds__(256) zker(const int* __restrict__ in_ids,
                                            const int* __restrict__ out_ids,
                                            const float* __restrict__ emb,
                                            const float* __restrict__ enc_wih,
                                            const float* __restrict__ enc_bih,
                                            const float* __restrict__ enc_bhh,
                                            const float* __restrict__ dec_wih,
                                            const float* __restrict__ dec_bih,
                                            const float* __restrict__ dec_bhh,
                                            float* __restrict__ z) {
    int t = blockIdx.x;
    const float *wih, *bih, *bhh;
    int id;
    if (t < 512) {
        wih = enc_wih; bih = enc_bih; bhh = enc_bhh; id = in_ids[t];
    } else {
        wih = dec_wih; bih = dec_bih; bhh = dec_bhh;
        id = (t == 512) ? 1 : out_ids[t - 513];
    }
    __shared__ float x[EDIM];
    x[threadIdx.x] = emb[(long)id * EDIM + threadIdx.x];
    __syncthreads();
#pragma unroll
    for (int rr = 0; rr < 2; ++rr) {
        int r = threadIdx.x + rr * 256;
        const float4* w4 = (const float4*)(wih + r * EDIM);
        float acc = 0.f;
#pragma unroll 8
        for (int k4 = 0; k4 < 64; ++k4) {
            float4 wv = w4[k4];
            acc += wv.x * x[k4 * 4 + 0] + wv.y * x[k4 * 4 + 1] +
                   wv.z * x[k4 * 4 + 2] + wv.w * x[k4 * 4 + 3];
        }
        z[t * HDIM + r] = acc + bih[r] + bhh[r];
    }
}

// ---------------------------------------------------------------------------
// Sequential RNN scan: single workgroup, 512 threads (8 waves).
// thread tid: rg = tid>>3 (row group), c = tid&7 (k chunk of 64).
// Computes partials for rows rg*8+jr over k=[c*64,c*64+64); rows 0..5 weights in
// VGPRs (192 regs), rows 6..7 streamed from LDS. h kept as f16 in LDS, double
// buffered, granule(16B)-XOR-swizzled so the 8 distinct broadcast reads per
// wave-instruction hit 8 distinct bank groups. Fold-reduce over the 8 c-lanes
// leaves lane c with the full sum of row rg*8+c == tid. One barrier per step.
// ---------------------------------------------------------------------------
__global__ void __launch_bounds__(512, 2) scan_ker(
    const _Float16* __restrict__ wpack,   // [64][512][8] f16
    const float* __restrict__ z,          // [nsteps][512] f32
    const _Float16* __restrict__ h_init,  // null => zeros; else [512] plain
    _Float16* __restrict__ hs_out,        // null or [nsteps][512] plain
    _Float16* __restrict__ hfin_out,      // null or [512] plain
    int nsteps) {
    __shared__ uint4 wlds[16 * 512];   // 128 KB: rows jr=6,7: [(jr-6)*8 + i][tid]
    __shared__ uint4 hbuf[2][64];      // 2 KB: h as f16, swizzled granules

    const int tid = threadIdx.x;
    const int c = tid & 7;
    // physical granule for h element `tid` (row == tid after fold-reduce):
    // logical granule G = tid>>3; c_of = G>>3; i_of = G&7; phys = c_of*8 + (i_of^c_of)
    const int c_of = tid >> 6;
    const int i_of = (tid >> 3) & 7;
    const int hphys = (c_of << 3) | (i_of ^ c_of);

    const uint4* wp4 = (const uint4*)wpack;
    uint32_t wreg[192];
#pragma unroll
    for (int g = 0; g < 48; ++g) {
        uint4 v = wp4[g * 512 + tid];
        wreg[g * 4 + 0] = v.x; wreg[g * 4 + 1] = v.y;
        wreg[g * 4 + 2] = v.z; wreg[g * 4 + 3] = v.w;
    }
#pragma unroll
    for (int g = 48; g < 64; ++g) wlds[(g - 48) * 512 + tid] = wp4[g * 512 + tid];

    {
        _Float16 hv = (_Float16)0.f;
        if (h_init) hv = h_init[tid];
        ((_Float16*)hbuf[0])[hphys * 8 + (tid & 7)] = hv;
    }
    __syncthreads();

    int cur = 0;
    for (int t = 0; t < nsteps; ++t) {
        float zv = z[t * HDIM + tid];          // independent: scheduled early
        const uint4* hb = hbuf[cur];
        float acc[8] = {0.f, 0.f, 0.f, 0.f, 0.f, 0.f, 0.f, 0.f};
#pragma unroll
        for (int i = 0; i < 8; ++i) {
            uint4 hg = hb[(c << 3) | (i ^ c)];
#pragma unroll
            for (int jr = 0; jr < 6; ++jr) {
                acc[jr] = dot2(wreg[(jr * 8 + i) * 4 + 0], hg.x, acc[jr]);
                acc[jr] = dot2(wreg[(jr * 8 + i) * 4 + 1], hg.y, acc[jr]);
                acc[jr] = dot2(wreg[(jr * 8 + i) * 4 + 2], hg.z, acc[jr]);
                acc[jr] = dot2(wreg[(jr * 8 + i) * 4 + 3], hg.w, acc[jr]);
            }
            uint4 w6 = wlds[i * 512 + tid];
            uint4 w7 = wlds[(8 + i) * 512 + tid];
            acc[6] = dot2(w6.x, hg.x, acc[6]);
            acc[6] = dot2(w6.y, hg.y, acc[6]);
            acc[6] = dot2(w6.z, hg.z, acc[6]);
            acc[6] = dot2(w6.w, hg.w, acc[6]);
            acc[7] = dot2(w7.x, hg.x, acc[7]);
            acc[7] = dot2(w7.y, hg.y, acc[7]);
            acc[7] = dot2(w7.z, hg.z, acc[7]);
            acc[7] = dot2(w7.w, hg.w, acc[7]);
        }
        // fold-reduce over lane bits 0..2: lane c ends with row rg*8+c (== tid)
        float s, keep, b0, b1, b2, b3, d0, d1, v;
#define FOLD(aL, aH, bit, mask, dst)            \
        s = (c & bit) ? (aL) : (aH);            \
        s = __shfl_xor(s, mask, 64);            \
        keep = (c & bit) ? (aH) : (aL);         \
        dst = keep + s;
        FOLD(acc[0], acc[1], 1, 1, b0)
        FOLD(acc[2], acc[3], 1, 1, b1)
        FOLD(acc[4], acc[5], 1, 1, b2)
        FOLD(acc[6], acc[7], 1, 1, b3)
        FOLD(b0, b1, 2, 2, d0)
        FOLD(b2, b3, 2, 2, d1)
        FOLD(d0, d1, 4, 4, v)
#undef FOLD
        float hnew = tanhf(v + zv);
        _Float16 h16v = (_Float16)hnew;
        ((_Float16*)hbuf[cur ^ 1])[hphys * 8 + (tid & 7)] = h16v;
        if (hs_out) hs_out[t * HDIM + tid] = h16v;
        if (hfin_out && t == nsteps - 1) hfin_out[tid] = h16v;
        __syncthreads();
        cur ^= 1;
    }
}

// ---------------------------------------------------------------------------
// FC: out[m][n] = sum_k A16[m][k] * fc_w[n][k] + fc_b[n]
// M=512, N=50257, K=512. f16 MFMA 16x16x32, LDS-free (direct global frags).
// Block 256 thr = 4 waves (2x2), each wave 64x64, 4x4 frags.
// ---------------------------------------------------------------------------
__global__ void __launch_bounds__(256) fc_ker(const _Float16* __restrict__ A,
                                              const float* __restrict__ Bw,
                                              const float* __restrict__ bias,
                                              float* __restrict__ out) {
    int n0 = blockIdx.x * 128, m0 = blockIdx.y * 128;
    int w = threadIdx.x >> 6, l = threadIdx.x & 63;
    int wm = (w >> 1) * 64, wn = (w & 1) * 64;
    int lr = l & 15, lk = (l >> 4) * 8;

    float4_t acc[4][4];
#pragma unroll
    for (int fm = 0; fm < 4; ++fm)
#pragma unroll
        for (int fn = 0; fn < 4; ++fn) acc[fm][fn] = (float4_t){0.f, 0.f, 0.f, 0.f};

    for (int ks = 0; ks < 512; ks += 32) {
        half8_t a[4], b[4];
#pragma unroll
        for (int f = 0; f < 4; ++f) {
            int m = m0 + wm + f * 16 + lr;
            a[f] = *(const half8_t*)(A + (long)m * 512 + ks + lk);
            int n = n0 + wn + f * 16 + lr;
            half8_t bb;
            if (n < CDIM) {
                const float4* bp4 = (const float4*)(Bw + (long)n * 512 + ks + lk);
                float4 x0 = bp4[0], x1 = bp4[1];
                bb[0] = (_Float16)x0.x; bb[1] = (_Float16)x0.y;
                bb[2] = (_Float16)x0.z; bb[3] = (_Float16)x0.w;
                bb[4] = (_Float16)x1.x; bb[5] = (_Float16)x1.y;
                bb[6] = (_Float16)x1.z; bb[7] = (_Float16)x1.w;
            } else {
#pragma unroll
                for (int e = 0; e < 8; ++e) bb[e] = (_Float16)0.f;
            }
            b[f] = bb;
        }
#pragma unroll
        for (int fm = 0; fm < 4; ++fm)
#pragma unroll
            for (int fn = 0; fn < 4; ++fn)
                acc[fm][fn] = __builtin_amdgcn_mfma_f32_16x16x32_f16(
                    a[fm], b[fn], acc[fm][fn], 0, 0, 0);
    }
#pragma unroll
    for (int fn = 0; fn < 4; ++fn) {
        int n = n0 + wn + fn * 16 + lr;
        if (n >= CDIM) continue;
        float bv = bias[n];
#pragma unroll
        for (int fm = 0; fm < 4; ++fm) {
#pragma unroll
            for (int q = 0; q < 4; ++q) {
                int m = m0 + wm + fm * 16 + (l >> 4) * 4 + q;
                out[(long)m * CDIM + n] = acc[fm][fn][q] + bv;
            }
        }
    }
}

// ---------------------------------------------------------------------------
// Workspace layout (needs ~3.7 MB):
//   [0, 2MB)          z  f32 [1024][512]
//   [2MB, 2.5MB)      wpack_enc f16
//   [2.5MB, 3MB)      wpack_dec f16
//   [3MB, 3.5MB)      h16 f16 [512][512]  (decoder hidden states = FC A matrix)
//   [3.5MB, +1KB)     hn16 f16 [512]      (encoder final hidden)
// ---------------------------------------------------------------------------
extern "C" void kernel_launch(void* const* d_in, const int* in_sizes, int n_in,
                              void* d_out, int out_size, void* d_ws, size_t ws_size,
                              hipStream_t stream) {
    const int* input_ids  = (const int*)d_in[1];
    const int* output_ids = (const int*)d_in[2];
    const float* emb      = (const float*)d_in[3];
    const float* enc_wih  = (const float*)d_in[4];
    const float* enc_whh  = (const float*)d_in[5];
    const float* enc_bih  = (const float*)d_in[6];
    const float* enc_bhh  = (const float*)d_in[7];
    const float* dec_wih  = (const float*)d_in[8];
    const float* dec_whh  = (const float*)d_in[9];
    const float* dec_bih  = (const float*)d_in[10];
    const float* dec_bhh  = (const float*)d_in[11];
    const float* fc_w     = (const float*)d_in[12];
    const float* fc_b     = (const float*)d_in[13];
    float* out = (float*)d_out;

    char* ws = (char*)d_ws;
    float* z        = (float*)ws;                                  // 2 MB
    _Float16* wpe   = (_Float16*)(ws + (2u << 20));                // 512 KB
    _Float16* wpd   = (_Float16*)(ws + (2u << 20) + (512u << 10)); // 512 KB
    _Float16* h16   = (_Float16*)(ws + (3u << 20));                // 512 KB
    _Float16* hn16  = (_Float16*)(ws + (3u << 20) + (512u << 10)); // 1 KB

    pack_whh<<<128, 256, 0, stream>>>(enc_whh, wpe);
    pack_whh<<<128, 256, 0, stream>>>(dec_whh, wpd);
    zker<<<1024, 256, 0, stream>>>(input_ids, output_ids, emb,
                                   enc_wih, enc_bih, enc_bhh,
                                   dec_wih, dec_bih, dec_bhh, z);
    // encoder: h starts at 0, produce hn16
    scan_ker<<<1, 512, 0, stream>>>(wpe, z, nullptr, nullptr, hn16, 512);
    // decoder: h starts at hn16, produce all 512 hidden states
    scan_ker<<<1, 512, 0, stream>>>(wpd, z + 512 * HDIM, hn16, h16, nullptr, 512);
    fc_ker<<<dim3((CDIM + 127) / 128, 4), 256, 0, stream>>>(h16, fc_w, fc_b, out);
}